// Round 10
// baseline (465.844 us; speedup 1.0000x reference)
//
#include <hip/hip_runtime.h>

typedef unsigned long long u64;
typedef unsigned int u32;

#define MAXN 8704            // 8700 rounded to 64
#define MAXNW 144
#define CHUNK 512            // j-chunk for rank kernel
#define EC 4096              // edge-word slots per source chunk (~50x headroom)
#define EFAST 512            // LDS-staged edges per chunk (fast path)

// direct global->LDS copy: 64 lanes x 16B. Side-effecting intrinsic: the
// compiler can NOT sink it to the use site (the round-8 failure mode where
// readonly register "prefetches" were legally re-materialized at use).
__device__ __forceinline__ void gl2lds16(const void* g, void* l) {
    __builtin_amdgcn_global_load_lds(
        (const __attribute__((address_space(1))) void*)g,
        (__attribute__((address_space(3))) void*)l, 16, 0, 0);
}

// ---------------- K0: merge + clip + cxcywh->xyxy + sort key + ws init ------
__global__ void prep_kernel(const float* __restrict__ yb, const float* __restrict__ yc,
                            const float* __restrict__ db, const float* __restrict__ dc,
                            int n1, int n,
                            float4* __restrict__ xyxy, float* __restrict__ conf,
                            u32* __restrict__ key, int* __restrict__ rank,
                            u64* __restrict__ diag_g, u64* __restrict__ tb1,
                            int* __restrict__ ecnt) {
    int i = blockIdx.x * 256 + threadIdx.x;
    if (i < MAXN) { rank[i] = 0; diag_g[i] = 0; tb1[i] = 0; }
    if (i < MAXNW) ecnt[i] = 0;
    if (i >= n) return;
    float cx, cy, w, h, c;
    if (i < n1) {
        const float* b = yb + (size_t)i * 4;
        cx = b[0]; cy = b[1]; w = b[2]; h = b[3]; c = yc[i];
    } else {
        const float* b = db + (size_t)(i - n1) * 4;
        cx = b[0]; cy = b[1]; w = b[2]; h = b[3]; c = dc[i - n1];
    }
    c = fminf(fmaxf(c, 0.0f), 1.0f);
    float hw = w * 0.5f, hh = h * 0.5f;
    xyxy[i] = make_float4(cx - hw, cy - hh, cx + hw, cy + hh);
    conf[i] = c;
    key[i]  = __float_as_uint(c);
}

// ---------------- K1: O(N^2) stable rank ------------------------------------
__global__ void rank_kernel(const u32* __restrict__ key, int n, int* __restrict__ rank) {
    __shared__ __align__(16) u32 sk[CHUNK];
    int t = threadIdx.x;
    int jbase = blockIdx.y * CHUNK;
    for (int s = t; s < CHUNK; s += 256) {
        int j = jbase + s;
        sk[s] = (j < n) ? key[j] : 0u;
    }
    __syncthreads();
    int i = blockIdx.x * 256 + t;
    if (i >= n) return;
    u32 ki = key[i];
    int cnt = 0;
    const uint4* sk4 = (const uint4*)sk;
    for (int s = 0; s < CHUNK / 4; ++s) {
        uint4 k = sk4[s];
        int j = jbase + s * 4;
        cnt += (k.x > ki) || (k.x == ki && (j + 0) < i);
        cnt += (k.y > ki) || (k.y == ki && (j + 1) < i);
        cnt += (k.z > ki) || (k.z == ki && (j + 2) < i);
        cnt += (k.w > ki) || (k.w == ki && (j + 3) < i);
    }
    if (cnt) atomicAdd(&rank[i], cnt);
}

// ---------------- K2: scatter into sorted order -----------------------------
__global__ void scatter_kernel(const float4* __restrict__ xyxy, const float* __restrict__ conf,
                               const int* __restrict__ rank, int n,
                               float4* __restrict__ sbox, float* __restrict__ sconf) {
    int i = blockIdx.x * 256 + threadIdx.x;
    if (i >= n) return;
    int r = rank[i];
    sbox[r]  = xyxy[i];
    sconf[r] = conf[i];
}

// ---------------- K3: SPARSE suppression structure ---------------------------
// d=0 -> diag_g[i]; d=1 -> tb1[j] transposed (bit r: source row r suppresses
// target row j of next chunk); d>=2 & word!=0 -> edge {(row<<8)|bj, mask}.
__global__ void iou_kernel(const float4* __restrict__ sbox, int n, int nw,
                           u64* __restrict__ diag_g, u64* __restrict__ tb1,
                           u32* __restrict__ einfo, u64* __restrict__ emask,
                           int* __restrict__ ecnt) {
    int bi = blockIdx.y, bj = blockIdx.x;
    if (bj < bi) return;
    __shared__ float4 cb[64];
    __shared__ float4 cb2[64];
    int t  = threadIdx.x;
    int j0 = bj * 64;
    int jt = j0 + t;
    int d  = bj - bi;
    float4 myj = (jt < n) ? sbox[jt] : make_float4(0, 0, 0, 0);
    cb[t] = myj;
    if (d == 1) cb2[t] = (bi * 64 + t < n) ? sbox[bi * 64 + t] : make_float4(0, 0, 0, 0);
    __syncthreads();

    if (d == 1) {
        float areaT = (myj.z - myj.x) * (myj.w - myj.y);
        u64 w2 = 0;
        for (int k = 0; k < 64; ++k) {
            float4 b = cb2[k];
            float iw = fmaxf(fminf(b.z, myj.z) - fmaxf(b.x, myj.x), 0.0f);
            float ih = fmaxf(fminf(b.w, myj.w) - fmaxf(b.y, myj.y), 0.0f);
            float inter = iw * ih;
            float areaB = (b.z - b.x) * (b.w - b.y);
            float uni = areaB + areaT - inter;
            float iou = inter / fmaxf(uni, 1e-9f);
            if (iou > 0.5f) w2 |= (1ULL << k);
        }
        tb1[(size_t)j0 + t] = w2;
        return;
    }

    int i = bi * 64 + t;
    if (i >= n) return;
    float4 a = sbox[i];
    float areaA = (a.z - a.x) * (a.w - a.y);
    u64 word = 0;
    int kmax = min(64, n - j0);
    for (int k = 0; k < kmax; ++k) {
        int j = j0 + k;
        float4 b = cb[k];
        float iw = fmaxf(fminf(a.z, b.z) - fmaxf(a.x, b.x), 0.0f);
        float ih = fmaxf(fminf(a.w, b.w) - fmaxf(a.y, b.y), 0.0f);
        float inter = iw * ih;
        float areaB = (b.z - b.x) * (b.w - b.y);
        float uni = areaA + areaB - inter;
        float iou = inter / fmaxf(uni, 1e-9f);
        if (j > i && iou > 0.5f) word |= (1ULL << k);
    }
    if (d == 0) diag_g[i] = word;
    else if (word) {
        int slot = atomicAdd(&ecnt[bi], 1);
        if (slot < EC) {
            einfo[(size_t)bi * EC + slot] = ((u32)t << 8) | (u32)bj;
            emask[(size_t)bi * EC + slot] = word;
        }
    }
}

// ---------------- K4: single-wave NMS with LDS-staged streaming -------------
// Wave 0 runs the verified round-8 chain; all per-chunk data streams via
// global_load_lds into a 3-slot rotating LDS area (8 fixed loads/phase,
// counted vmcnt(8) at phase top).
// Slot invariant at top of phase p (after vmcnt(8)): batches <= p+1 LANDED,
// batch p+2 in flight. Reads this phase: diag slot (p+1)%3 [chunk p+1, ok],
// tb slot (p+1)%3 [chunk p+1, ok -- ROUND-9 BUG was reading chunk p+2],
// edges slot p%3 [chunk p, ok].
// Per phase p: drain; nxt=s_remv[p+1] (ds-ordered after prev applies);
// TB=tb[p+1] (used in THIS phase's ballot, latency hidden by solve);
// BUn=diag[p+1] (carried); ctz-solve diag p; r1=ballot(TB&kw); apply chunk
// p's edges from LDS (targets >= p+2); CUR=nxt|r1; issue batch p+3.
// Coverage: word w = diag(w) + ballot(w-1) + edges q<=w-2 applied at q.
__global__ __launch_bounds__(512) void nms_scan(const u64* __restrict__ diag_g,
                                                const u64* __restrict__ tb1,
                                                const u32* __restrict__ einfo,
                                                const u64* __restrict__ emask,
                                                const int* __restrict__ ecnt,
                                                const float* __restrict__ sbox,
                                                const float* __restrict__ sconf,
                                                int n, int nw,
                                                float* __restrict__ out) {
    __shared__ u64 s_remv[MAXNW];
    __shared__ u64 s_kws[MAXNW];
    __shared__ int s_cnt[MAXNW];
    __shared__ u64 ld_diag[3][128];
    __shared__ u64 ld_tb[3][128];
    __shared__ u32 ld_einfo[3][EFAST];
    __shared__ u64 ld_emask[3][EFAST];

    int t = threadIdx.x;

    if (t < 64) {
        for (int i = t; i < MAXNW; i += 64) {
            s_remv[i] = 0; s_kws[i] = 0;
            s_cnt[i] = (i < nw) ? min(ecnt[i], EC) : 0;
        }

        // ---- batch issue helper (8 global_load_lds, chunk cc -> slot sl) ----
        #define ISSUE_BATCH(cc_, sl_) do {                                        \
            int cc = (cc_); int slq = (sl_);                                      \
            gl2lds16(diag_g + (size_t)cc * 64 + t * 2, &ld_diag[slq][0]);         \
            gl2lds16(tb1    + (size_t)cc * 64 + t * 2, &ld_tb[slq][0]);           \
            const u32* ei_ = einfo + (size_t)cc * EC;                             \
            const u64* em_ = emask + (size_t)cc * EC;                             \
            gl2lds16(ei_ + t * 4,       &ld_einfo[slq][0]);                       \
            gl2lds16(ei_ + t * 4 + 256, &ld_einfo[slq][256]);                     \
            gl2lds16(em_ + t * 2,       &ld_emask[slq][0]);                       \
            gl2lds16(em_ + t * 2 + 128, &ld_emask[slq][128]);                     \
            gl2lds16(em_ + t * 2 + 256, &ld_emask[slq][256]);                     \
            gl2lds16(em_ + t * 2 + 384, &ld_emask[slq][384]);                     \
        } while (0)

        // prologue: fill slots 0,1,2 with chunks 0,1,2
        ISSUE_BATCH(min(0, nw - 1), 0);
        ISSUE_BATCH(min(1, nw - 1), 1);
        ISSUE_BATCH(min(2, nw - 1), 2);
        asm volatile("s_waitcnt vmcnt(8)" ::: "memory");   // batches 0,1 landed
        __builtin_amdgcn_sched_barrier(0);

        u64 BU  = ld_diag[0][t];                       // diag chunk 0 (phase 0)
        u64 CUR = 0;

        int sl = 0;
        for (int p = 0; p < nw; ++p) {
            asm volatile("s_waitcnt vmcnt(8)" ::: "memory");  // batches <= p+1 landed
            __builtin_amdgcn_sched_barrier(0);
            int sl1 = (sl == 2) ? 0 : sl + 1;

            // early off-chain LDS reads (all from LANDED batches <= p+1)
            u64 nxt = s_remv[min(p + 1, MAXNW - 1)];   // ordered after prev applies
            u64 TB  = ld_tb[sl1][t];                   // tb chunk p+1: THIS phase's ballot
            u64 BUn = ld_diag[sl1][t];                 // diag chunk p+1: next phase

            // ---- solve chunk p (ctz-skip chain, diag slices in lane regs) ----
            int rem = n - (p << 6);
            u64 vm = (rem >= 64) ? ~0ull : (rem <= 0 ? 0ull : ((1ull << rem) - 1ull));
            u64 cand = ~CUR & vm;
            u64 kw = 0;
            u32 dlo = (u32)BU, dhi = (u32)(BU >> 32);
            while (cand) {
                int k1 = __builtin_amdgcn_readfirstlane((int)__builtin_ctzll(cand));
                u64 s1 = (((u64)(u32)__builtin_amdgcn_readlane((int)dhi, k1)) << 32)
                       |  ((u64)(u32)__builtin_amdgcn_readlane((int)dlo, k1));
                u64 c1 = cand & ~(1ull << k1);
                kw |= 1ull << k1;
                if (c1) {   // speculative second candidate
                    int k2 = __builtin_amdgcn_readfirstlane((int)__builtin_ctzll(c1));
                    u64 s2 = (((u64)(u32)__builtin_amdgcn_readlane((int)dhi, k2)) << 32)
                           |  ((u64)(u32)__builtin_amdgcn_readlane((int)dlo, k2));
                    if (!((s1 >> k2) & 1ull)) {
                        kw |= 1ull << k2;
                        cand = c1 & ~(1ull << k2) & ~(s1 | s2);
                    } else {
                        cand = c1 & ~s1;
                    }
                } else cand = 0;
            }
            if (t == 0) s_kws[p] = kw;

            // ---- near update: ballot over transposed band (tb chunk p+1) ----
            u64 r1 = __ballot((TB & kw) != 0ull);

            // ---- apply chunk p's edges from LDS (targets >= p+2) ----
            int cq = s_cnt[p];
            #pragma unroll
            for (int j = 0; j < 8; ++j) {
                int s2i = t + j * 64;
                if (s2i < cq) {
                    u32 ei = ld_einfo[sl][s2i];
                    u64 em = ld_emask[sl][s2i];
                    if ((kw >> (ei >> 8)) & 1ull)
                        atomicOr((unsigned long long*)&s_remv[ei & 255u],
                                 (unsigned long long)em);
                }
            }
            if (cq > EFAST) {      // never-expected overflow: straight global
                for (int s2i = EFAST + t; s2i < cq; s2i += 64) {
                    u32 ei = einfo[(size_t)p * EC + s2i];
                    u64 em = emask[(size_t)p * EC + s2i];
                    if ((kw >> (ei >> 8)) & 1ull)
                        atomicOr((unsigned long long*)&s_remv[ei & 255u],
                                 (unsigned long long)em);
                }
            }

            CUR = nxt | r1;
            BU = BUn;

            // ---- issue batch for phase p+3 into the just-freed slot ----
            __builtin_amdgcn_sched_barrier(0);
            ISSUE_BATCH(min(p + 3, nw - 1), sl);
            sl = sl1;
        }
        #undef ISSUE_BATCH
    }
    __syncthreads();   // waves 1-7 waited here; s_kws now visible

    // ---- masked output (all 512 threads) ----
    for (int e = t; e < n * 5; e += 512) {
        int r = e / 5, c5 = e - r * 5;
        float keep = ((s_kws[r >> 6] >> (r & 63)) & 1ull) ? 1.0f : 0.0f;
        float v = (c5 < 4) ? sbox[(size_t)r * 4 + c5] : sconf[r];
        out[e] = v * keep;
    }
}

// ---------------- launch -----------------------------------------------------
extern "C" void kernel_launch(void* const* d_in, const int* in_sizes, int n_in,
                              void* d_out, int out_size, void* d_ws, size_t ws_size,
                              hipStream_t stream) {
    const float* yb = (const float*)d_in[0];
    const float* yc = (const float*)d_in[1];
    const float* db = (const float*)d_in[2];
    const float* dc = (const float*)d_in[3];
    int n1 = in_sizes[1];
    int n2 = in_sizes[3];
    int n  = n1 + n2;                          // 8700
    int nw = (n + 63) / 64;                    // 136

    char* w = (char*)d_ws;
    u64*    diag_g = (u64*)w;                                  // MAXN + 64 pad (1KB reads)
    u64*    tb1    = diag_g + MAXN + 64;                       // MAXN + 64 pad
    u64*    emask  = tb1 + MAXN + 64;                          // MAXNW*EC u64
    u32*    einfo  = (u32*)(emask + (size_t)MAXNW * EC);       // MAXNW*EC u32
    int*    ecnt   = (int*)(einfo + (size_t)MAXNW * EC);       // MAXNW ints
    float4* xyxy   = (float4*)(ecnt + MAXNW);
    float4* sbox   = xyxy + MAXN;
    float*  conf   = (float*)(sbox + MAXN);
    float*  sconf  = conf + MAXN;
    u32*    key    = (u32*)(sconf + MAXN);
    int*    rank   = (int*)(key + MAXN);

    int nb = (n + 255) / 256;                                  // 34
    prep_kernel<<<nb, 256, 0, stream>>>(yb, yc, db, dc, n1, n, xyxy, conf, key, rank,
                                        diag_g, tb1, ecnt);

    dim3 g1(nb, (n + CHUNK - 1) / CHUNK);                      // 34 x 17
    rank_kernel<<<g1, 256, 0, stream>>>(key, n, rank);

    scatter_kernel<<<nb, 256, 0, stream>>>(xyxy, conf, rank, n, sbox, sconf);

    dim3 g3(nw, nw);                                           // 136 x 136 (upper tri active)
    iou_kernel<<<g3, 64, 0, stream>>>(sbox, n, nw, diag_g, tb1, einfo, emask, ecnt);

    nms_scan<<<1, 512, 0, stream>>>(diag_g, tb1, einfo, emask, ecnt,
                                    (const float*)sbox, sconf, n, nw, (float*)d_out);
}